// Round 1
// baseline (941.189 us; speedup 1.0000x reference)
//
#include <hip/hip_runtime.h>
#include <hip/hip_bf16.h>

#define N_NODES 10000
#define DFEAT 512
#define EDGE_CAP 600000

// ---------------- pass 1: scan adjacency rows, collect edges + column degrees ----------------
__global__ __launch_bounds__(256) void scan_rows(const float* __restrict__ A,
                                                 int* __restrict__ deg,
                                                 int2* __restrict__ edges,
                                                 int* __restrict__ ecount) {
    const int row = blockIdx.x;
    const int tid = threadIdx.x;
    __shared__ int2 lbuf[256];
    __shared__ int lcount;
    __shared__ int gbase;
    if (tid == 0) lcount = 0;
    __syncthreads();
    const float4* Arow = (const float4*)(A + (size_t)row * N_NODES);
    for (int c = tid; c < N_NODES / 4; c += 256) {
        float4 v = Arow[c];
        float vv[4] = {v.x, v.y, v.z, v.w};
#pragma unroll
        for (int k = 0; k < 4; ++k) {
            if (vv[k] != 0.0f) {
                int j = c * 4 + k;
                atomicAdd(&deg[j], 1);
                int p = atomicAdd(&lcount, 1);
                if (p < 256) lbuf[p] = make_int2(row, j);
            }
        }
    }
    __syncthreads();
    int cnt = min(lcount, 256);
    if (tid == 0) gbase = atomicAdd(ecount, cnt);
    __syncthreads();
    for (int p = tid; p < cnt; p += 256) {
        int g = gbase + p;
        if (g < EDGE_CAP) edges[g] = lbuf[p];
    }
}

// ---------------- dinv[j] = (deg[j] + 1)^-1/2 ----------------
__global__ void compute_dinv(const int* __restrict__ deg, float* __restrict__ dinv) {
    int j = blockIdx.x * 256 + threadIdx.x;
    if (j < N_NODES) dinv[j] = 1.0f / sqrtf((float)(deg[j] + 1));
}

// ---------------- exclusive prefix sum of degrees -> CSC offsets ----------------
__global__ __launch_bounds__(256) void scan_offsets(const int* __restrict__ deg,
                                                    int* __restrict__ offsets) {
    __shared__ int part[256];
    const int tid = threadIdx.x;
    const int base = tid * 40;  // 256*40 = 10240 >= 10000
    int s = 0;
    for (int k = 0; k < 40; ++k) {
        int idx = base + k;
        if (idx < N_NODES) s += deg[idx];
    }
    part[tid] = s;
    __syncthreads();
    for (int off = 1; off < 256; off <<= 1) {
        int v = (tid >= off) ? part[tid - off] : 0;
        __syncthreads();
        part[tid] += v;
        __syncthreads();
    }
    int run = (tid > 0) ? part[tid - 1] : 0;
    for (int k = 0; k < 40; ++k) {
        int idx = base + k;
        if (idx < N_NODES) {
            offsets[idx] = run;
            run += deg[idx];
        }
    }
    if (tid == 255) offsets[N_NODES] = part[255];
}

// ---------------- bin edges by target column ----------------
__global__ void bin_edges(const int2* __restrict__ edges, const int* __restrict__ ecount,
                          const int* __restrict__ offsets, int* __restrict__ cursor,
                          int* __restrict__ csc) {
    int e = blockIdx.x * 256 + threadIdx.x;
    int E = min(*ecount, EDGE_CAP);
    if (e < E) {
        int2 ij = edges[e];
        int pos = atomicAdd(&cursor[ij.y], 1);
        csc[offsets[ij.y] + pos] = ij.x;
    }
}

// ---------------- fp32 GEMM: C[M,512] = A[M,512] @ B[512,512] ----------------
__global__ __launch_bounds__(256) void gemm_512(const float* __restrict__ A,
                                                const float* __restrict__ B,
                                                float* __restrict__ C, int M) {
    __shared__ float As[64][17];
    __shared__ float Bs[16][64];
    const int tid = threadIdx.x;
    const int tx = tid & 15, ty = tid >> 4;
    const int row0 = blockIdx.y * 64;
    const int col0 = blockIdx.x * 64;
    const int arow = tid >> 2, acol = (tid & 3) * 4;
    const int brow = tid >> 4, bcol = (tid & 15) * 4;
    float acc[4][4] = {};
    for (int k0 = 0; k0 < 512; k0 += 16) {
        float4 av = make_float4(0.f, 0.f, 0.f, 0.f);
        int gr = row0 + arow;
        if (gr < M) av = *(const float4*)(A + (size_t)gr * 512 + k0 + acol);
        As[arow][acol + 0] = av.x;
        As[arow][acol + 1] = av.y;
        As[arow][acol + 2] = av.z;
        As[arow][acol + 3] = av.w;
        float4 bv = *(const float4*)(B + (size_t)(k0 + brow) * 512 + col0 + bcol);
        *(float4*)(&Bs[brow][bcol]) = bv;
        __syncthreads();
#pragma unroll
        for (int k = 0; k < 16; ++k) {
            float a0 = As[ty * 4 + 0][k];
            float a1 = As[ty * 4 + 1][k];
            float a2 = As[ty * 4 + 2][k];
            float a3 = As[ty * 4 + 3][k];
            float b0 = Bs[k][tx * 4 + 0];
            float b1 = Bs[k][tx * 4 + 1];
            float b2 = Bs[k][tx * 4 + 2];
            float b3 = Bs[k][tx * 4 + 3];
            acc[0][0] += a0 * b0; acc[0][1] += a0 * b1; acc[0][2] += a0 * b2; acc[0][3] += a0 * b3;
            acc[1][0] += a1 * b0; acc[1][1] += a1 * b1; acc[1][2] += a1 * b2; acc[1][3] += a1 * b3;
            acc[2][0] += a2 * b0; acc[2][1] += a2 * b1; acc[2][2] += a2 * b2; acc[2][3] += a2 * b3;
            acc[3][0] += a3 * b0; acc[3][1] += a3 * b1; acc[3][2] += a3 * b2; acc[3][3] += a3 * b3;
        }
        __syncthreads();
    }
#pragma unroll
    for (int r = 0; r < 4; ++r) {
        int gr = row0 + ty * 4 + r;
        if (gr < M) {
            float4 o = make_float4(acc[r][0], acc[r][1], acc[r][2], acc[r][3]);
            *(float4*)(C + (size_t)gr * 512 + col0 + tx * 4) = o;
        }
    }
}

// ---------------- sparse aggregate: out[j] = relu(dinv[j]*(dinv[j]*H[j] + sum dinv[i]*H[i]) + b) ----------------
__global__ __launch_bounds__(128) void aggregate(const float* __restrict__ H,
                                                 const float* __restrict__ dinv,
                                                 const int* __restrict__ offsets,
                                                 const int* __restrict__ csc,
                                                 const float* __restrict__ bias,
                                                 float* __restrict__ out) {
    const int j = blockIdx.x;
    const int tid = threadIdx.x;  // 128 threads * float4 = 512
    __shared__ int sidx[128];
    __shared__ float sw[128];
    const float dj = dinv[j];
    float4 v = ((const float4*)(H + (size_t)j * DFEAT))[tid];
    float4 acc = make_float4(dj * v.x, dj * v.y, dj * v.z, dj * v.w);
    int s = offsets[j];
    const int e = offsets[j + 1];
    while (s < e) {
        int chunk = min(128, e - s);
        __syncthreads();
        if (tid < chunk) {
            int i = csc[s + tid];
            sidx[tid] = i;
            sw[tid] = dinv[i];
        }
        __syncthreads();
        for (int c = 0; c < chunk; ++c) {
            float4 u = ((const float4*)(H + (size_t)sidx[c] * DFEAT))[tid];
            float w = sw[c];
            acc.x += w * u.x;
            acc.y += w * u.y;
            acc.z += w * u.z;
            acc.w += w * u.w;
        }
        s += chunk;
    }
    float4 b = ((const float4*)bias)[tid];
    float4 o;
    o.x = fmaxf(dj * acc.x + b.x, 0.0f);
    o.y = fmaxf(dj * acc.y + b.y, 0.0f);
    o.z = fmaxf(dj * acc.z + b.z, 0.0f);
    o.w = fmaxf(dj * acc.w + b.w, 0.0f);
    *(float4*)(out + (size_t)j * DFEAT + tid * 4) = o;
}

extern "C" void kernel_launch(void* const* d_in, const int* in_sizes, int n_in,
                              void* d_out, int out_size, void* d_ws, size_t ws_size,
                              hipStream_t stream) {
    const float* x  = (const float*)d_in[0];
    const float* A  = (const float*)d_in[1];
    const float* W1 = (const float*)d_in[2];
    const float* b1 = (const float*)d_in[3];
    const float* W2 = (const float*)d_in[4];
    const float* b2 = (const float*)d_in[5];
    float* out = (float*)d_out;

    char* ws = (char*)d_ws;
    size_t off = 0;
    auto alloc = [&](size_t bytes) -> void* {
        void* p = ws + off;
        off = (off + bytes + 255) & ~(size_t)255;
        return p;
    };
    float* XW   = (float*)alloc((size_t)N_NODES * DFEAT * 4);
    float* H1   = (float*)alloc((size_t)N_NODES * DFEAT * 4);
    float* dinv = (float*)alloc((size_t)N_NODES * 4);
    int*   deg  = (int*)alloc((size_t)N_NODES * 4);   // start of zeroed region
    int* cursor = (int*)alloc((size_t)N_NODES * 4);
    int* ecount = (int*)alloc(256);                   // end of zeroed region
    int*  offs  = (int*)alloc((size_t)(N_NODES + 1) * 4);
    int2* edges = (int2*)alloc((size_t)EDGE_CAP * 8);
    int*  csc   = (int*)alloc((size_t)EDGE_CAP * 4);

    // zero deg, cursor, ecount in one shot (contiguous region incl. padding)
    size_t zbytes = (size_t)((char*)ecount - (char*)deg) + 256;
    hipMemsetAsync(deg, 0, zbytes, stream);

    scan_rows<<<N_NODES, 256, 0, stream>>>(A, deg, edges, ecount);
    compute_dinv<<<(N_NODES + 255) / 256, 256, 0, stream>>>(deg, dinv);
    scan_offsets<<<1, 256, 0, stream>>>(deg, offs);
    bin_edges<<<(EDGE_CAP + 255) / 256, 256, 0, stream>>>(edges, ecount, offs, cursor, csc);

    dim3 ggrid(DFEAT / 64, (N_NODES + 63) / 64);
    gemm_512<<<ggrid, 256, 0, stream>>>(x, W1, XW, N_NODES);
    aggregate<<<N_NODES, 128, 0, stream>>>(XW, dinv, offs, csc, b1, H1);
    gemm_512<<<ggrid, 256, 0, stream>>>(H1, W2, XW, N_NODES);
    aggregate<<<N_NODES, 128, 0, stream>>>(XW, dinv, offs, csc, b2, out);
}

// Round 2
// 845.886 us; speedup vs baseline: 1.1127x; 1.1127x over previous
//
#include <hip/hip_runtime.h>
#include <hip/hip_bf16.h>

#define N_NODES 10000
#define DFEAT 512
#define MPAD 10112   // 79 * 128
#define EDGE_CAP 600000

typedef __attribute__((ext_vector_type(8))) short short8x;
typedef __attribute__((ext_vector_type(4))) float f32x4;

__device__ __forceinline__ ushort f2bf(float f) {
    uint u = __builtin_bit_cast(uint, f);
    uint r = (u + 0x7FFFu + ((u >> 16) & 1u)) >> 16;
    return (ushort)r;
}
__device__ __forceinline__ float bf2f(ushort h) {
    uint u = ((uint)h) << 16;
    return __builtin_bit_cast(float, u);
}

typedef const __attribute__((address_space(1))) void gv_t;
typedef __attribute__((address_space(3))) void sv_t;
__device__ __forceinline__ void gload16(const void* g, void* l) {
    __builtin_amdgcn_global_load_lds((gv_t*)g, (sv_t*)l, 16, 0, 0);
}

// ---------------- pass 1: scan adjacency rows, collect edges + column degrees ----------------
__global__ __launch_bounds__(256) void scan_rows(const float* __restrict__ A,
                                                 int* __restrict__ deg,
                                                 int2* __restrict__ edges,
                                                 int* __restrict__ ecount) {
    const int row = blockIdx.x;
    const int tid = threadIdx.x;
    __shared__ int2 lbuf[256];
    __shared__ int lcount;
    __shared__ int gbase;
    if (tid == 0) lcount = 0;
    __syncthreads();
    const float4* Arow = (const float4*)(A + (size_t)row * N_NODES);
    for (int c = tid; c < N_NODES / 4; c += 256) {
        float4 v = Arow[c];
        float vv[4] = {v.x, v.y, v.z, v.w};
#pragma unroll
        for (int k = 0; k < 4; ++k) {
            if (vv[k] != 0.0f) {
                int j = c * 4 + k;
                atomicAdd(&deg[j], 1);
                int p = atomicAdd(&lcount, 1);
                if (p < 256) lbuf[p] = make_int2(row, j);
            }
        }
    }
    __syncthreads();
    int cnt = min(lcount, 256);
    if (tid == 0) gbase = atomicAdd(ecount, cnt);
    __syncthreads();
    for (int p = tid; p < cnt; p += 256) {
        int g = gbase + p;
        if (g < EDGE_CAP) edges[g] = lbuf[p];
    }
}

// ---------------- dinv[j] = (deg[j] + 1)^-1/2 ----------------
__global__ void compute_dinv(const int* __restrict__ deg, float* __restrict__ dinv) {
    int j = blockIdx.x * 256 + threadIdx.x;
    if (j < N_NODES) dinv[j] = 1.0f / sqrtf((float)(deg[j] + 1));
}

// ---------------- exclusive prefix sum of degrees -> CSC offsets ----------------
__global__ __launch_bounds__(256) void scan_offsets(const int* __restrict__ deg,
                                                    int* __restrict__ offsets) {
    __shared__ int part[256];
    const int tid = threadIdx.x;
    const int base = tid * 40;
    int s = 0;
    for (int k = 0; k < 40; ++k) {
        int idx = base + k;
        if (idx < N_NODES) s += deg[idx];
    }
    part[tid] = s;
    __syncthreads();
    for (int off = 1; off < 256; off <<= 1) {
        int v = (tid >= off) ? part[tid - off] : 0;
        __syncthreads();
        part[tid] += v;
        __syncthreads();
    }
    int run = (tid > 0) ? part[tid - 1] : 0;
    for (int k = 0; k < 40; ++k) {
        int idx = base + k;
        if (idx < N_NODES) {
            offsets[idx] = run;
            run += deg[idx];
        }
    }
    if (tid == 255) offsets[N_NODES] = part[255];
}

// ---------------- bin edges by target column ----------------
__global__ void bin_edges(const int2* __restrict__ edges, const int* __restrict__ ecount,
                          const int* __restrict__ offsets, int* __restrict__ cursor,
                          int* __restrict__ csc) {
    int e = blockIdx.x * 256 + threadIdx.x;
    int E = min(*ecount, EDGE_CAP);
    if (e < E) {
        int2 ij = edges[e];
        int pos = atomicAdd(&cursor[ij.y], 1);
        csc[offsets[ij.y] + pos] = ij.x;
    }
}

// ---------------- split fp32 rows into bf16 hi/lo (pad rows -> 0) ----------------
__global__ __launch_bounds__(256) void split_rows(const float* __restrict__ X,
                                                  ushort* __restrict__ Xh,
                                                  ushort* __restrict__ Xl) {
    size_t idx = (size_t)blockIdx.x * 256 + threadIdx.x;   // over MPAD*128 float4s
    if (idx >= (size_t)MPAD * 128) return;
    int row = (int)(idx >> 7);
    float4 v = make_float4(0.f, 0.f, 0.f, 0.f);
    if (row < N_NODES) v = ((const float4*)X)[idx];
    ushort4 hi, lo;
    hi.x = f2bf(v.x); lo.x = f2bf(v.x - bf2f(hi.x));
    hi.y = f2bf(v.y); lo.y = f2bf(v.y - bf2f(hi.y));
    hi.z = f2bf(v.z); lo.z = f2bf(v.z - bf2f(hi.z));
    hi.w = f2bf(v.w); lo.w = f2bf(v.w - bf2f(hi.w));
    ((ushort4*)Xh)[idx] = hi;
    ((ushort4*)Xl)[idx] = lo;
}

// ---------------- split + transpose W: WT[n][k] bf16 hi/lo ----------------
__global__ __launch_bounds__(256) void split_w_t(const float* __restrict__ W,
                                                 ushort* __restrict__ WhT,
                                                 ushort* __restrict__ WlT) {
    __shared__ float tile[32][33];
    const int k0 = blockIdx.y * 32;
    const int n0 = blockIdx.x * 32;
    const int tx = threadIdx.x & 31, ty = threadIdx.x >> 5;
#pragma unroll
    for (int p = 0; p < 4; ++p)
        tile[ty + p * 8][tx] = W[(size_t)(k0 + ty + p * 8) * DFEAT + n0 + tx];
    __syncthreads();
#pragma unroll
    for (int p = 0; p < 4; ++p) {
        int n = n0 + ty + p * 8;
        int k = k0 + tx;
        float v = tile[tx][ty + p * 8];
        ushort h = f2bf(v);
        WhT[(size_t)n * DFEAT + k] = h;
        WlT[(size_t)n * DFEAT + k] = f2bf(v - bf2f(h));
    }
}

// ---------------- bf16x3 MFMA GEMM: C[M,512] = (Ah+Al)[Mpad,512] @ (Wh+Wl)T ----------------
// Tile: BM=128, BN=64, BK=64. 256 threads = 4 waves (2x2), wave tile 64x32.
__global__ __launch_bounds__(256) void gemm_bf16x3(const ushort* __restrict__ Ah,
                                                   const ushort* __restrict__ Al,
                                                   const ushort* __restrict__ BhT,
                                                   const ushort* __restrict__ BlT,
                                                   float* __restrict__ C, int M) {
    __shared__ ushort lAh[128 * 64];
    __shared__ ushort lAl[128 * 64];
    __shared__ ushort lBh[64 * 64];
    __shared__ ushort lBl[64 * 64];
    const int tid = threadIdx.x;
    const int lane = tid & 63, wv = tid >> 6;
    const int row0 = blockIdx.y * 128, col0 = blockIdx.x * 64;
    const int wm = wv >> 1, wn = wv & 1;
    const int l15 = lane & 15, lg = lane >> 4;

    f32x4 acc[4][2];
#pragma unroll
    for (int i = 0; i < 4; ++i)
#pragma unroll
        for (int j = 0; j < 2; ++j) acc[i][j] = (f32x4){0.f, 0.f, 0.f, 0.f};

    for (int k0 = 0; k0 < 512; k0 += 64) {
        // ---- stage A tiles (16KB each): lds linear dest, inverse-swizzled global src
#pragma unroll
        for (int c = 0; c < 4; ++c) {
            int o = wv * 4096 + c * 1024 + lane * 16;
            int r = o >> 7;
            int kbs = o & 127;
            int kb = kbs ^ ((r & 7) << 4);
            size_t goff = (size_t)(row0 + r) * (DFEAT * 2) + (size_t)(k0 * 2) + kb;
            gload16((const char*)Ah + goff, (char*)lAh + (o - lane * 16));
            gload16((const char*)Al + goff, (char*)lAl + (o - lane * 16));
        }
        // ---- stage B tiles (8KB each) from transposed W
#pragma unroll
        for (int c = 0; c < 2; ++c) {
            int o = wv * 2048 + c * 1024 + lane * 16;
            int r = o >> 7;
            int kbs = o & 127;
            int kb = kbs ^ ((r & 7) << 4);
            size_t goff = (size_t)(col0 + r) * (DFEAT * 2) + (size_t)(k0 * 2) + kb;
            gload16((const char*)BhT + goff, (char*)lBh + (o - lane * 16));
            gload16((const char*)BlT + goff, (char*)lBl + (o - lane * 16));
        }
        __syncthreads();  // drains vmcnt -> LDS visible

#pragma unroll
        for (int s = 0; s < 2; ++s) {
            short8x a_h[4], a_l[4], b_h[2], b_l[2];
#pragma unroll
            for (int i = 0; i < 4; ++i) {
                int r = wm * 64 + i * 16 + l15;
                int kbs = (s * 64 + 16 * lg) ^ ((r & 7) << 4);
                a_h[i] = *(const short8x*)((const char*)lAh + r * 128 + kbs);
                a_l[i] = *(const short8x*)((const char*)lAl + r * 128 + kbs);
            }
#pragma unroll
            for (int j = 0; j < 2; ++j) {
                int n = wn * 32 + j * 16 + l15;
                int kbs = (s * 64 + 16 * lg) ^ ((n & 7) << 4);
                b_h[j] = *(const short8x*)((const char*)lBh + n * 128 + kbs);
                b_l[j] = *(const short8x*)((const char*)lBl + n * 128 + kbs);
            }
#pragma unroll
            for (int i = 0; i < 4; ++i)
#pragma unroll
                for (int j = 0; j < 2; ++j) {
                    acc[i][j] = __builtin_amdgcn_mfma_f32_16x16x32_bf16(a_h[i], b_h[j], acc[i][j], 0, 0, 0);
                    acc[i][j] = __builtin_amdgcn_mfma_f32_16x16x32_bf16(a_h[i], b_l[j], acc[i][j], 0, 0, 0);
                    acc[i][j] = __builtin_amdgcn_mfma_f32_16x16x32_bf16(a_l[i], b_h[j], acc[i][j], 0, 0, 0);
                }
        }
        __syncthreads();
    }

    // epilogue: C/D layout col = lane&15, row = 4*(lane>>4) + reg  [m89-verified]
#pragma unroll
    for (int i = 0; i < 4; ++i)
#pragma unroll
        for (int j = 0; j < 2; ++j) {
            int gcol = col0 + wn * 32 + j * 16 + l15;
#pragma unroll
            for (int r = 0; r < 4; ++r) {
                int grow = row0 + wm * 64 + i * 16 + lg * 4 + r;
                if (grow < M) C[(size_t)grow * DFEAT + gcol] = acc[i][j][r];
            }
        }
}

// ---------------- sparse aggregate (fp32 out) ----------------
__global__ __launch_bounds__(128) void aggregate(const float* __restrict__ H,
                                                 const float* __restrict__ dinv,
                                                 const int* __restrict__ offsets,
                                                 const int* __restrict__ csc,
                                                 const float* __restrict__ bias,
                                                 float* __restrict__ out) {
    const int j = blockIdx.x;
    const int tid = threadIdx.x;
    __shared__ int sidx[128];
    __shared__ float sw[128];
    const float dj = dinv[j];
    float4 v = ((const float4*)(H + (size_t)j * DFEAT))[tid];
    float4 acc = make_float4(dj * v.x, dj * v.y, dj * v.z, dj * v.w);
    int s = offsets[j];
    const int e = offsets[j + 1];
    while (s < e) {
        int chunk = min(128, e - s);
        __syncthreads();
        if (tid < chunk) {
            int i = csc[s + tid];
            sidx[tid] = i;
            sw[tid] = dinv[i];
        }
        __syncthreads();
        for (int c = 0; c < chunk; ++c) {
            float4 u = ((const float4*)(H + (size_t)sidx[c] * DFEAT))[tid];
            float w = sw[c];
            acc.x += w * u.x; acc.y += w * u.y; acc.z += w * u.z; acc.w += w * u.w;
        }
        s += chunk;
    }
    float4 b = ((const float4*)bias)[tid];
    float4 o;
    o.x = fmaxf(dj * acc.x + b.x, 0.0f);
    o.y = fmaxf(dj * acc.y + b.y, 0.0f);
    o.z = fmaxf(dj * acc.z + b.z, 0.0f);
    o.w = fmaxf(dj * acc.w + b.w, 0.0f);
    *(float4*)(out + (size_t)j * DFEAT + tid * 4) = o;
}

// ---------------- sparse aggregate with fused bf16 hi/lo split output ----------------
__global__ __launch_bounds__(128) void aggregate_split(const float* __restrict__ H,
                                                       const float* __restrict__ dinv,
                                                       const int* __restrict__ offsets,
                                                       const int* __restrict__ csc,
                                                       const float* __restrict__ bias,
                                                       ushort* __restrict__ Hh,
                                                       ushort* __restrict__ Hl) {
    const int j = blockIdx.x;
    const int tid = threadIdx.x;
    __shared__ int sidx[128];
    __shared__ float sw[128];
    const float dj = dinv[j];
    float4 v = ((const float4*)(H + (size_t)j * DFEAT))[tid];
    float4 acc = make_float4(dj * v.x, dj * v.y, dj * v.z, dj * v.w);
    int s = offsets[j];
    const int e = offsets[j + 1];
    while (s < e) {
        int chunk = min(128, e - s);
        __syncthreads();
        if (tid < chunk) {
            int i = csc[s + tid];
            sidx[tid] = i;
            sw[tid] = dinv[i];
        }
        __syncthreads();
        for (int c = 0; c < chunk; ++c) {
            float4 u = ((const float4*)(H + (size_t)sidx[c] * DFEAT))[tid];
            float w = sw[c];
            acc.x += w * u.x; acc.y += w * u.y; acc.z += w * u.z; acc.w += w * u.w;
        }
        s += chunk;
    }
    float4 b = ((const float4*)bias)[tid];
    float4 o;
    o.x = fmaxf(dj * acc.x + b.x, 0.0f);
    o.y = fmaxf(dj * acc.y + b.y, 0.0f);
    o.z = fmaxf(dj * acc.z + b.z, 0.0f);
    o.w = fmaxf(dj * acc.w + b.w, 0.0f);
    ushort4 hi, lo;
    hi.x = f2bf(o.x); lo.x = f2bf(o.x - bf2f(hi.x));
    hi.y = f2bf(o.y); lo.y = f2bf(o.y - bf2f(hi.y));
    hi.z = f2bf(o.z); lo.z = f2bf(o.z - bf2f(hi.z));
    hi.w = f2bf(o.w); lo.w = f2bf(o.w - bf2f(hi.w));
    ((ushort4*)(Hh + (size_t)j * DFEAT))[tid] = hi;
    ((ushort4*)(Hl + (size_t)j * DFEAT))[tid] = lo;
}

extern "C" void kernel_launch(void* const* d_in, const int* in_sizes, int n_in,
                              void* d_out, int out_size, void* d_ws, size_t ws_size,
                              hipStream_t stream) {
    const float* x  = (const float*)d_in[0];
    const float* A  = (const float*)d_in[1];
    const float* W1 = (const float*)d_in[2];
    const float* b1 = (const float*)d_in[3];
    const float* W2 = (const float*)d_in[4];
    const float* b2 = (const float*)d_in[5];
    float* out = (float*)d_out;

    char* ws = (char*)d_ws;
    size_t off = 0;
    auto alloc = [&](size_t bytes) -> void* {
        void* p = ws + off;
        off = (off + bytes + 255) & ~(size_t)255;
        return p;
    };
    float*  XW   = (float*)alloc((size_t)N_NODES * DFEAT * 4);
    ushort* Ah   = (ushort*)alloc((size_t)MPAD * DFEAT * 2);
    ushort* Al   = (ushort*)alloc((size_t)MPAD * DFEAT * 2);
    ushort* Hh   = (ushort*)alloc((size_t)MPAD * DFEAT * 2);
    ushort* Hl   = (ushort*)alloc((size_t)MPAD * DFEAT * 2);
    ushort* W1hT = (ushort*)alloc((size_t)DFEAT * DFEAT * 2);
    ushort* W1lT = (ushort*)alloc((size_t)DFEAT * DFEAT * 2);
    ushort* W2hT = (ushort*)alloc((size_t)DFEAT * DFEAT * 2);
    ushort* W2lT = (ushort*)alloc((size_t)DFEAT * DFEAT * 2);
    float*  dinv = (float*)alloc((size_t)N_NODES * 4);
    int*    deg  = (int*)alloc((size_t)N_NODES * 4);   // start of zeroed region
    int*  cursor = (int*)alloc((size_t)N_NODES * 4);
    int*  ecount = (int*)alloc(256);                   // end of zeroed region
    int*    offs = (int*)alloc((size_t)(N_NODES + 1) * 4);
    int2*  edges = (int2*)alloc((size_t)EDGE_CAP * 8);
    int*     csc = (int*)alloc((size_t)EDGE_CAP * 4);

    size_t zbytes = (size_t)((char*)ecount - (char*)deg) + 256;
    hipMemsetAsync(deg, 0, zbytes, stream);

    // graph preprocessing
    scan_rows<<<N_NODES, 256, 0, stream>>>(A, deg, edges, ecount);
    compute_dinv<<<(N_NODES + 255) / 256, 256, 0, stream>>>(deg, dinv);
    scan_offsets<<<1, 256, 0, stream>>>(deg, offs);
    bin_edges<<<(EDGE_CAP + 255) / 256, 256, 0, stream>>>(edges, ecount, offs, cursor, csc);

    // split inputs to bf16 hi/lo
    split_rows<<<(MPAD * 128 + 255) / 256, 256, 0, stream>>>(x, Ah, Al);
    dim3 wgrid(16, 16);
    split_w_t<<<wgrid, 256, 0, stream>>>(W1, W1hT, W1lT);
    split_w_t<<<wgrid, 256, 0, stream>>>(W2, W2hT, W2lT);

    // layer 1
    dim3 ggrid(DFEAT / 64, MPAD / 128);
    gemm_bf16x3<<<ggrid, 256, 0, stream>>>(Ah, Al, W1hT, W1lT, XW, N_NODES);
    aggregate_split<<<N_NODES, 128, 0, stream>>>(XW, dinv, offs, csc, b1, Hh, Hl);

    // layer 2  (Hh/Hl pad rows hold poison; affected C rows are >= N_NODES and never written)
    gemm_bf16x3<<<ggrid, 256, 0, stream>>>(Hh, Hl, W2hT, W2lT, XW, N_NODES);
    aggregate<<<N_NODES, 128, 0, stream>>>(XW, dinv, offs, csc, b2, out);
}

// Round 3
// 841.937 us; speedup vs baseline: 1.1179x; 1.0047x over previous
//
#include <hip/hip_runtime.h>
#include <hip/hip_bf16.h>

#define N_NODES 10000
#define DFEAT 512
#define MPAD 10112   // 79 * 128
#define EDGE_CAP 600000

typedef __attribute__((ext_vector_type(8))) short short8x;
typedef __attribute__((ext_vector_type(4))) float f32x4;

__device__ __forceinline__ ushort f2bf(float f) {
    uint u = __builtin_bit_cast(uint, f);
    uint r = (u + 0x7FFFu + ((u >> 16) & 1u)) >> 16;
    return (ushort)r;
}
__device__ __forceinline__ float bf2f(ushort h) {
    uint u = ((uint)h) << 16;
    return __builtin_bit_cast(float, u);
}

typedef const __attribute__((address_space(1))) void gv_t;
typedef __attribute__((address_space(3))) void sv_t;
__device__ __forceinline__ void gload16(const void* g, void* l) {
    __builtin_amdgcn_global_load_lds((gv_t*)g, (sv_t*)l, 16, 0, 0);
}

// ---------------- pass 1: scan adjacency rows, collect edges + column degrees ----------------
__global__ __launch_bounds__(256) void scan_rows(const float* __restrict__ A,
                                                 int* __restrict__ deg,
                                                 int2* __restrict__ edges,
                                                 int* __restrict__ ecount) {
    const int row = blockIdx.x;
    const int tid = threadIdx.x;
    __shared__ int2 lbuf[256];
    __shared__ int lcount;
    __shared__ int gbase;
    if (tid == 0) lcount = 0;
    __syncthreads();
    const float4* Arow = (const float4*)(A + (size_t)row * N_NODES);
    for (int c = tid; c < N_NODES / 4; c += 256) {
        float4 v = Arow[c];
        float vv[4] = {v.x, v.y, v.z, v.w};
#pragma unroll
        for (int k = 0; k < 4; ++k) {
            if (vv[k] != 0.0f) {
                int j = c * 4 + k;
                atomicAdd(&deg[j], 1);
                int p = atomicAdd(&lcount, 1);
                if (p < 256) lbuf[p] = make_int2(row, j);
            }
        }
    }
    __syncthreads();
    int cnt = min(lcount, 256);
    if (tid == 0) gbase = atomicAdd(ecount, cnt);
    __syncthreads();
    for (int p = tid; p < cnt; p += 256) {
        int g = gbase + p;
        if (g < EDGE_CAP) edges[g] = lbuf[p];
    }
}

// ---------------- prefix sum of degrees -> CSC offsets, fused dinv ----------------
__global__ __launch_bounds__(256) void scan_offsets(const int* __restrict__ deg,
                                                    int* __restrict__ offsets,
                                                    float* __restrict__ dinv) {
    __shared__ int part[256];
    const int tid = threadIdx.x;
    const int base = tid * 40;
    int s = 0;
    for (int k = 0; k < 40; ++k) {
        int idx = base + k;
        if (idx < N_NODES) s += deg[idx];
    }
    part[tid] = s;
    __syncthreads();
    for (int off = 1; off < 256; off <<= 1) {
        int v = (tid >= off) ? part[tid - off] : 0;
        __syncthreads();
        part[tid] += v;
        __syncthreads();
    }
    int run = (tid > 0) ? part[tid - 1] : 0;
    for (int k = 0; k < 40; ++k) {
        int idx = base + k;
        if (idx < N_NODES) {
            offsets[idx] = run;
            dinv[idx] = 1.0f / sqrtf((float)(deg[idx] + 1));
            run += deg[idx];
        }
    }
    if (tid == 255) offsets[N_NODES] = part[255];
}

// ---------------- bin edges by target column ----------------
__global__ void bin_edges(const int2* __restrict__ edges, const int* __restrict__ ecount,
                          const int* __restrict__ offsets, int* __restrict__ cursor,
                          int* __restrict__ csc) {
    int e = blockIdx.x * 256 + threadIdx.x;
    int E = min(*ecount, EDGE_CAP);
    if (e < E) {
        int2 ij = edges[e];
        int pos = atomicAdd(&cursor[ij.y], 1);
        csc[offsets[ij.y] + pos] = ij.x;
    }
}

// ---------------- split fp32 rows into bf16 hi/lo (pad rows -> 0) ----------------
__global__ __launch_bounds__(256) void split_rows(const float* __restrict__ X,
                                                  ushort* __restrict__ Xh,
                                                  ushort* __restrict__ Xl) {
    size_t idx = (size_t)blockIdx.x * 256 + threadIdx.x;
    if (idx >= (size_t)MPAD * 128) return;
    int row = (int)(idx >> 7);
    float4 v = make_float4(0.f, 0.f, 0.f, 0.f);
    if (row < N_NODES) v = ((const float4*)X)[idx];
    ushort4 hi, lo;
    hi.x = f2bf(v.x); lo.x = f2bf(v.x - bf2f(hi.x));
    hi.y = f2bf(v.y); lo.y = f2bf(v.y - bf2f(hi.y));
    hi.z = f2bf(v.z); lo.z = f2bf(v.z - bf2f(hi.z));
    hi.w = f2bf(v.w); lo.w = f2bf(v.w - bf2f(hi.w));
    ((ushort4*)Xh)[idx] = hi;
    ((ushort4*)Xl)[idx] = lo;
}

// ---------------- split + transpose W: WT[n][k] bf16 hi/lo ----------------
__global__ __launch_bounds__(256) void split_w_t(const float* __restrict__ W,
                                                 ushort* __restrict__ WhT,
                                                 ushort* __restrict__ WlT) {
    __shared__ float tile[32][33];
    const int k0 = blockIdx.y * 32;
    const int n0 = blockIdx.x * 32;
    const int tx = threadIdx.x & 31, ty = threadIdx.x >> 5;
#pragma unroll
    for (int p = 0; p < 4; ++p)
        tile[ty + p * 8][tx] = W[(size_t)(k0 + ty + p * 8) * DFEAT + n0 + tx];
    __syncthreads();
#pragma unroll
    for (int p = 0; p < 4; ++p) {
        int n = n0 + ty + p * 8;
        int k = k0 + tx;
        float v = tile[tx][ty + p * 8];
        ushort h = f2bf(v);
        WhT[(size_t)n * DFEAT + k] = h;
        WlT[(size_t)n * DFEAT + k] = f2bf(v - bf2f(h));
    }
}

// ---- bf16x3 MFMA GEMM with fused dinv prescale: C[m,:] = dinv[m] * ((Ah+Al)@(Bh+Bl)T)[m,:]
// Tile: BM=128, BN=128, BK=64. 256 threads = 4 waves (2x2), wave tile 64x64.
__global__ __launch_bounds__(256, 2) void gemm_bf16x3(const ushort* __restrict__ Ah,
                                                      const ushort* __restrict__ Al,
                                                      const ushort* __restrict__ BhT,
                                                      const ushort* __restrict__ BlT,
                                                      const float* __restrict__ dinv,
                                                      float* __restrict__ C, int M) {
    __shared__ ushort lAh[128 * 64];
    __shared__ ushort lAl[128 * 64];
    __shared__ ushort lBh[128 * 64];
    __shared__ ushort lBl[128 * 64];
    const int tid = threadIdx.x;
    const int lane = tid & 63, wv = tid >> 6;
    const int row0 = blockIdx.y * 128, col0 = blockIdx.x * 128;
    const int wm = wv >> 1, wn = wv & 1;
    const int l15 = lane & 15, lg = lane >> 4;

    f32x4 acc[4][4];
#pragma unroll
    for (int i = 0; i < 4; ++i)
#pragma unroll
        for (int j = 0; j < 4; ++j) acc[i][j] = (f32x4){0.f, 0.f, 0.f, 0.f};

    for (int k0 = 0; k0 < 512; k0 += 64) {
        // stage 4x16KB tiles: linear LDS dest, inverse-swizzled global source
#pragma unroll
        for (int c = 0; c < 4; ++c) {
            int o = wv * 4096 + c * 1024 + lane * 16;
            int r = o >> 7;
            int kb = (o & 127) ^ ((r & 7) << 4);
            size_t ga = (size_t)(row0 + r) * 1024 + (size_t)(k0 * 2) + kb;
            size_t gb = (size_t)(col0 + r) * 1024 + (size_t)(k0 * 2) + kb;
            int ldst = o - lane * 16;
            gload16((const char*)Ah + ga, (char*)lAh + ldst);
            gload16((const char*)Al + ga, (char*)lAl + ldst);
            gload16((const char*)BhT + gb, (char*)lBh + ldst);
            gload16((const char*)BlT + gb, (char*)lBl + ldst);
        }
        __syncthreads();

#pragma unroll
        for (int s = 0; s < 2; ++s) {
            short8x a_h[4], a_l[4], b_h[4], b_l[4];
#pragma unroll
            for (int i = 0; i < 4; ++i) {
                int r = wm * 64 + i * 16 + l15;
                int kbs = (s * 64 + 16 * lg) ^ ((r & 7) << 4);
                a_h[i] = *(const short8x*)((const char*)lAh + r * 128 + kbs);
                a_l[i] = *(const short8x*)((const char*)lAl + r * 128 + kbs);
            }
#pragma unroll
            for (int j = 0; j < 4; ++j) {
                int n = wn * 64 + j * 16 + l15;
                int kbs = (s * 64 + 16 * lg) ^ ((n & 7) << 4);
                b_h[j] = *(const short8x*)((const char*)lBh + n * 128 + kbs);
                b_l[j] = *(const short8x*)((const char*)lBl + n * 128 + kbs);
            }
#pragma unroll
            for (int i = 0; i < 4; ++i)
#pragma unroll
                for (int j = 0; j < 4; ++j) {
                    acc[i][j] = __builtin_amdgcn_mfma_f32_16x16x32_bf16(a_h[i], b_h[j], acc[i][j], 0, 0, 0);
                    acc[i][j] = __builtin_amdgcn_mfma_f32_16x16x32_bf16(a_h[i], b_l[j], acc[i][j], 0, 0, 0);
                    acc[i][j] = __builtin_amdgcn_mfma_f32_16x16x32_bf16(a_l[i], b_h[j], acc[i][j], 0, 0, 0);
                }
        }
        __syncthreads();
    }

    // epilogue: C/D layout col = lane&15, row = 4*(lane>>4)+reg; fused dinv prescale
#pragma unroll
    for (int i = 0; i < 4; ++i) {
#pragma unroll
        for (int r = 0; r < 4; ++r) {
            int grow = row0 + wm * 64 + i * 16 + lg * 4 + r;
            if (grow < M) {
                float dv = dinv[grow];
#pragma unroll
                for (int j = 0; j < 4; ++j) {
                    int gcol = col0 + wn * 64 + j * 16 + l15;
                    C[(size_t)grow * DFEAT + gcol] = dv * acc[i][j][r];
                }
            }
        }
    }
}

// ---------------- sparse aggregate core: acc = sum of prescaled rows {j} u N(j) ----------------
__device__ __forceinline__ float4 gather_sum(const float4* __restrict__ G4,
                                             const int* __restrict__ offsets,
                                             const int* __restrict__ csc,
                                             int* sidx, int j, int tid) {
    float4 acc = G4[(j << 7) + tid];  // self row (already dinv-prescaled)
    int s = offsets[j];
    const int e = offsets[j + 1];
    while (s < e) {
        int chunk = min(128, e - s);
        __syncthreads();
        if (tid < chunk) sidx[tid] = csc[s + tid];
        __syncthreads();
        int c = 0;
        for (; c + 8 <= chunk; c += 8) {
            float4 u[8];
#pragma unroll
            for (int q = 0; q < 8; ++q) u[q] = G4[(sidx[c + q] << 7) + tid];
#pragma unroll
            for (int q = 0; q < 8; ++q) {
                acc.x += u[q].x; acc.y += u[q].y; acc.z += u[q].z; acc.w += u[q].w;
            }
        }
        for (; c + 4 <= chunk; c += 4) {
            float4 u[4];
#pragma unroll
            for (int q = 0; q < 4; ++q) u[q] = G4[(sidx[c + q] << 7) + tid];
#pragma unroll
            for (int q = 0; q < 4; ++q) {
                acc.x += u[q].x; acc.y += u[q].y; acc.z += u[q].z; acc.w += u[q].w;
            }
        }
        for (; c < chunk; ++c) {
            float4 u = G4[(sidx[c] << 7) + tid];
            acc.x += u.x; acc.y += u.y; acc.z += u.z; acc.w += u.w;
        }
        s += chunk;
    }
    return acc;
}

// ---------------- aggregate, bf16 hi/lo split output (layer 1) ----------------
__global__ __launch_bounds__(128) void aggregate_split(const float* __restrict__ G,
                                                       const float* __restrict__ dinv,
                                                       const int* __restrict__ offsets,
                                                       const int* __restrict__ csc,
                                                       const float* __restrict__ bias,
                                                       ushort* __restrict__ Hh,
                                                       ushort* __restrict__ Hl) {
    const int j = blockIdx.x;
    const int tid = threadIdx.x;
    __shared__ int sidx[128];
    float4 acc = gather_sum((const float4*)G, offsets, csc, sidx, j, tid);
    const float dj = dinv[j];
    float4 b = ((const float4*)bias)[tid];
    float4 o;
    o.x = fmaxf(dj * acc.x + b.x, 0.0f);
    o.y = fmaxf(dj * acc.y + b.y, 0.0f);
    o.z = fmaxf(dj * acc.z + b.z, 0.0f);
    o.w = fmaxf(dj * acc.w + b.w, 0.0f);
    ushort4 hi, lo;
    hi.x = f2bf(o.x); lo.x = f2bf(o.x - bf2f(hi.x));
    hi.y = f2bf(o.y); lo.y = f2bf(o.y - bf2f(hi.y));
    hi.z = f2bf(o.z); lo.z = f2bf(o.z - bf2f(hi.z));
    hi.w = f2bf(o.w); lo.w = f2bf(o.w - bf2f(hi.w));
    ((ushort4*)(Hh + ((size_t)j << 9)))[tid] = hi;
    ((ushort4*)(Hl + ((size_t)j << 9)))[tid] = lo;
}

// ---------------- aggregate, fp32 output (layer 2) ----------------
__global__ __launch_bounds__(128) void aggregate_final(const float* __restrict__ G,
                                                       const float* __restrict__ dinv,
                                                       const int* __restrict__ offsets,
                                                       const int* __restrict__ csc,
                                                       const float* __restrict__ bias,
                                                       float* __restrict__ out) {
    const int j = blockIdx.x;
    const int tid = threadIdx.x;
    __shared__ int sidx[128];
    float4 acc = gather_sum((const float4*)G, offsets, csc, sidx, j, tid);
    const float dj = dinv[j];
    float4 b = ((const float4*)bias)[tid];
    float4 o;
    o.x = fmaxf(dj * acc.x + b.x, 0.0f);
    o.y = fmaxf(dj * acc.y + b.y, 0.0f);
    o.z = fmaxf(dj * acc.z + b.z, 0.0f);
    o.w = fmaxf(dj * acc.w + b.w, 0.0f);
    ((float4*)(out + ((size_t)j << 9)))[tid] = o;
}

extern "C" void kernel_launch(void* const* d_in, const int* in_sizes, int n_in,
                              void* d_out, int out_size, void* d_ws, size_t ws_size,
                              hipStream_t stream) {
    const float* x  = (const float*)d_in[0];
    const float* A  = (const float*)d_in[1];
    const float* W1 = (const float*)d_in[2];
    const float* b1 = (const float*)d_in[3];
    const float* W2 = (const float*)d_in[4];
    const float* b2 = (const float*)d_in[5];
    float* out = (float*)d_out;

    char* ws = (char*)d_ws;
    size_t off = 0;
    auto alloc = [&](size_t bytes) -> void* {
        void* p = ws + off;
        off = (off + bytes + 255) & ~(size_t)255;
        return p;
    };
    float*  XW   = (float*)alloc((size_t)N_NODES * DFEAT * 4);
    ushort* Ah   = (ushort*)alloc((size_t)MPAD * DFEAT * 2);
    ushort* Al   = (ushort*)alloc((size_t)MPAD * DFEAT * 2);
    ushort* Hh   = (ushort*)alloc((size_t)MPAD * DFEAT * 2);
    ushort* Hl   = (ushort*)alloc((size_t)MPAD * DFEAT * 2);
    ushort* W1hT = (ushort*)alloc((size_t)DFEAT * DFEAT * 2);
    ushort* W1lT = (ushort*)alloc((size_t)DFEAT * DFEAT * 2);
    ushort* W2hT = (ushort*)alloc((size_t)DFEAT * DFEAT * 2);
    ushort* W2lT = (ushort*)alloc((size_t)DFEAT * DFEAT * 2);
    float*  dinv = (float*)alloc((size_t)N_NODES * 4);
    int*    deg  = (int*)alloc((size_t)N_NODES * 4);   // start of zeroed region
    int*  cursor = (int*)alloc((size_t)N_NODES * 4);
    int*  ecount = (int*)alloc(256);                   // end of zeroed region
    int*    offs = (int*)alloc((size_t)(N_NODES + 1) * 4);
    int2*  edges = (int2*)alloc((size_t)EDGE_CAP * 8);
    int*     csc = (int*)alloc((size_t)EDGE_CAP * 4);

    size_t zbytes = (size_t)((char*)ecount - (char*)deg) + 256;
    hipMemsetAsync(deg, 0, zbytes, stream);

    // graph preprocessing
    scan_rows<<<N_NODES, 256, 0, stream>>>(A, deg, edges, ecount);
    scan_offsets<<<1, 256, 0, stream>>>(deg, offs, dinv);
    bin_edges<<<(EDGE_CAP + 255) / 256, 256, 0, stream>>>(edges, ecount, offs, cursor, csc);

    // split inputs to bf16 hi/lo
    split_rows<<<(MPAD * 128 + 255) / 256, 256, 0, stream>>>(x, Ah, Al);
    dim3 wgrid(16, 16);
    split_w_t<<<wgrid, 256, 0, stream>>>(W1, W1hT, W1lT);
    split_w_t<<<wgrid, 256, 0, stream>>>(W2, W2hT, W2lT);

    // layer 1: XW = dinv .* (x @ W1)  (prescaled rows)
    dim3 ggrid(DFEAT / 128, MPAD / 128);
    gemm_bf16x3<<<ggrid, 256, 0, stream>>>(Ah, Al, W1hT, W1lT, dinv, XW, N_NODES);
    aggregate_split<<<N_NODES, 128, 0, stream>>>(XW, dinv, offs, csc, b1, Hh, Hl);

    // layer 2
    gemm_bf16x3<<<ggrid, 256, 0, stream>>>(Hh, Hl, W2hT, W2lT, dinv, XW, N_NODES);
    aggregate_final<<<N_NODES, 128, 0, stream>>>(XW, dinv, offs, csc, b2, out);
}

// Round 4
// 731.456 us; speedup vs baseline: 1.2867x; 1.1510x over previous
//
#include <hip/hip_runtime.h>
#include <hip/hip_bf16.h>
#include <hip/hip_fp16.h>

#define N_NODES 10000
#define DFEAT 512
#define MPAD 10112   // 79 * 128
#define EDGE_CAP 600000
#define NB_SCAN 10000
#define NB_SPLITX 5056          // MPAD*128/256
#define NB_WSPLIT 512           // 256 per W
#define GEMM_BLOCKS 316         // 79 row-blocks * 4 col-blocks
#define BIN_BLOCKS ((EDGE_CAP + 255) / 256)

typedef __attribute__((ext_vector_type(8))) short short8x;
typedef __attribute__((ext_vector_type(4))) float f32x4;
typedef __attribute__((ext_vector_type(4))) _Float16 half4x;

__device__ __forceinline__ ushort f2bf(float f) {
    uint u = __builtin_bit_cast(uint, f);
    uint r = (u + 0x7FFFu + ((u >> 16) & 1u)) >> 16;
    return (ushort)r;
}
__device__ __forceinline__ float bf2f(ushort h) {
    uint u = ((uint)h) << 16;
    return __builtin_bit_cast(float, u);
}

typedef const __attribute__((address_space(1))) void gv_t;
typedef __attribute__((address_space(3))) void sv_t;
__device__ __forceinline__ void gload16(const void* g, void* l) {
    __builtin_amdgcn_global_load_lds((gv_t*)g, (sv_t*)l, 16, 0, 0);
}

// ================= mega prep: scan_rows | split_rows | split_w_t (all independent) =================
__global__ __launch_bounds__(256) void mega_prep(const float* __restrict__ A,
                                                 const float* __restrict__ X,
                                                 const float* __restrict__ W1,
                                                 const float* __restrict__ W2,
                                                 int* __restrict__ deg,
                                                 int2* __restrict__ edges,
                                                 int* __restrict__ ecount,
                                                 ushort* __restrict__ Ah,
                                                 ushort* __restrict__ Al,
                                                 ushort* __restrict__ W1hT,
                                                 ushort* __restrict__ W1lT,
                                                 ushort* __restrict__ W2hT,
                                                 ushort* __restrict__ W2lT) {
    __shared__ char smem[4352];
    const int bid = blockIdx.x;
    const int tid = threadIdx.x;

    if (bid < NB_SCAN) {
        // ---- scan one adjacency row: collect edges + column degrees ----
        int2* lbuf = (int2*)smem;
        int* lcount = (int*)(smem + 2048);
        int* gbase = (int*)(smem + 2056);
        const int row = bid;
        if (tid == 0) *lcount = 0;
        __syncthreads();
        const float4* Arow = (const float4*)(A + (size_t)row * N_NODES);
        for (int c = tid; c < N_NODES / 4; c += 256) {
            float4 v = Arow[c];
            float vv[4] = {v.x, v.y, v.z, v.w};
#pragma unroll
            for (int k = 0; k < 4; ++k) {
                if (vv[k] != 0.0f) {
                    int j = c * 4 + k;
                    atomicAdd(&deg[j], 1);
                    int p = atomicAdd(lcount, 1);
                    if (p < 256) lbuf[p] = make_int2(row, j);
                }
            }
        }
        __syncthreads();
        int cnt = min(*lcount, 256);
        if (tid == 0) *gbase = atomicAdd(ecount, cnt);
        __syncthreads();
        for (int p = tid; p < cnt; p += 256) {
            int g = *gbase + p;
            if (g < EDGE_CAP) edges[g] = lbuf[p];
        }
    } else if (bid < NB_SCAN + NB_SPLITX) {
        // ---- split x rows into bf16 hi/lo (pad rows -> 0) ----
        size_t idx = (size_t)(bid - NB_SCAN) * 256 + tid;
        int row = (int)(idx >> 7);
        float4 v = make_float4(0.f, 0.f, 0.f, 0.f);
        if (row < N_NODES) v = ((const float4*)X)[idx];
        ushort4 hi, lo;
        hi.x = f2bf(v.x); lo.x = f2bf(v.x - bf2f(hi.x));
        hi.y = f2bf(v.y); lo.y = f2bf(v.y - bf2f(hi.y));
        hi.z = f2bf(v.z); lo.z = f2bf(v.z - bf2f(hi.z));
        hi.w = f2bf(v.w); lo.w = f2bf(v.w - bf2f(hi.w));
        ((ushort4*)Ah)[idx] = hi;
        ((ushort4*)Al)[idx] = lo;
    } else {
        // ---- split + transpose W (bf16 hi/lo), 256 blocks per matrix ----
        int wb = bid - NB_SCAN - NB_SPLITX;  // 0..511
        const float* W = (wb < 256) ? W1 : W2;
        ushort* WhT = (wb < 256) ? W1hT : W2hT;
        ushort* WlT = (wb < 256) ? W1lT : W2lT;
        int wi = wb & 255;
        int n0 = (wi & 15) * 32, k0 = (wi >> 4) * 32;
        float(*tile)[33] = (float(*)[33])smem;  // 32*33*4 = 4224 B
        const int tx = tid & 31, ty = tid >> 5;
#pragma unroll
        for (int p = 0; p < 4; ++p)
            tile[ty + p * 8][tx] = W[(size_t)(k0 + ty + p * 8) * DFEAT + n0 + tx];
        __syncthreads();
#pragma unroll
        for (int p = 0; p < 4; ++p) {
            int n = n0 + ty + p * 8;
            int k = k0 + tx;
            float v = tile[tx][ty + p * 8];
            ushort h = f2bf(v);
            WhT[(size_t)n * DFEAT + k] = h;
            WlT[(size_t)n * DFEAT + k] = f2bf(v - bf2f(h));
        }
    }
}

// ---------------- prefix sum of degrees -> CSC offsets, fused dinv ----------------
__global__ __launch_bounds__(256) void scan_offsets(const int* __restrict__ deg,
                                                    int* __restrict__ offsets,
                                                    float* __restrict__ dinv) {
    __shared__ int part[256];
    const int tid = threadIdx.x;
    const int base = tid * 40;
    int s = 0;
    for (int k = 0; k < 40; ++k) {
        int idx = base + k;
        if (idx < N_NODES) s += deg[idx];
    }
    part[tid] = s;
    __syncthreads();
    for (int off = 1; off < 256; off <<= 1) {
        int v = (tid >= off) ? part[tid - off] : 0;
        __syncthreads();
        part[tid] += v;
        __syncthreads();
    }
    int run = (tid > 0) ? part[tid - 1] : 0;
    for (int k = 0; k < 40; ++k) {
        int idx = base + k;
        if (idx < N_NODES) {
            offsets[idx] = run;
            dinv[idx] = 1.0f / sqrtf((float)(deg[idx] + 1));
            run += deg[idx];
        }
    }
    if (tid == 255) offsets[N_NODES] = part[255];
}

// ---- bf16x3 MFMA GEMM tile body with fused dinv prescale, fp16 output ----
// C16[m,:] = (_Float16)(dinv[m] * ((Ah+Al) @ (Bh+Bl)^T)[m,:]).  BM=128,BN=128,BK=64.
__device__ __forceinline__ void gemm_tile(const ushort* __restrict__ Ah,
                                          const ushort* __restrict__ Al,
                                          const ushort* __restrict__ BhT,
                                          const ushort* __restrict__ BlT,
                                          const float* __restrict__ dinv,
                                          _Float16* __restrict__ C, int M,
                                          int row0, int col0, int tid) {
    __shared__ ushort lAh[128 * 64];
    __shared__ ushort lAl[128 * 64];
    __shared__ ushort lBh[128 * 64];
    __shared__ ushort lBl[128 * 64];
    const int lane = tid & 63, wv = tid >> 6;
    const int wm = wv >> 1, wn = wv & 1;
    const int l15 = lane & 15, lg = lane >> 4;

    f32x4 acc[4][4];
#pragma unroll
    for (int i = 0; i < 4; ++i)
#pragma unroll
        for (int j = 0; j < 4; ++j) acc[i][j] = (f32x4){0.f, 0.f, 0.f, 0.f};

    for (int k0 = 0; k0 < 512; k0 += 64) {
#pragma unroll
        for (int c = 0; c < 4; ++c) {
            int o = wv * 4096 + c * 1024 + lane * 16;
            int r = o >> 7;
            int kb = (o & 127) ^ ((r & 7) << 4);
            size_t ga = (size_t)(row0 + r) * 1024 + (size_t)(k0 * 2) + kb;
            size_t gb = (size_t)(col0 + r) * 1024 + (size_t)(k0 * 2) + kb;
            int ldst = o - lane * 16;
            gload16((const char*)Ah + ga, (char*)lAh + ldst);
            gload16((const char*)Al + ga, (char*)lAl + ldst);
            gload16((const char*)BhT + gb, (char*)lBh + ldst);
            gload16((const char*)BlT + gb, (char*)lBl + ldst);
        }
        __syncthreads();

#pragma unroll
        for (int s = 0; s < 2; ++s) {
            short8x a_h[4], a_l[4], b_h[4], b_l[4];
#pragma unroll
            for (int i = 0; i < 4; ++i) {
                int r = wm * 64 + i * 16 + l15;
                int kbs = (s * 64 + 16 * lg) ^ ((r & 7) << 4);
                a_h[i] = *(const short8x*)((const char*)lAh + r * 128 + kbs);
                a_l[i] = *(const short8x*)((const char*)lAl + r * 128 + kbs);
            }
#pragma unroll
            for (int j = 0; j < 4; ++j) {
                int n = wn * 64 + j * 16 + l15;
                int kbs = (s * 64 + 16 * lg) ^ ((n & 7) << 4);
                b_h[j] = *(const short8x*)((const char*)lBh + n * 128 + kbs);
                b_l[j] = *(const short8x*)((const char*)lBl + n * 128 + kbs);
            }
#pragma unroll
            for (int i = 0; i < 4; ++i)
#pragma unroll
                for (int j = 0; j < 4; ++j) {
                    acc[i][j] = __builtin_amdgcn_mfma_f32_16x16x32_bf16(a_h[i], b_h[j], acc[i][j], 0, 0, 0);
                    acc[i][j] = __builtin_amdgcn_mfma_f32_16x16x32_bf16(a_h[i], b_l[j], acc[i][j], 0, 0, 0);
                    acc[i][j] = __builtin_amdgcn_mfma_f32_16x16x32_bf16(a_l[i], b_h[j], acc[i][j], 0, 0, 0);
                }
        }
        __syncthreads();
    }

    // epilogue: C/D col = lane&15, row = 4*(lane>>4)+reg; dinv prescale; fp16 store
#pragma unroll
    for (int i = 0; i < 4; ++i) {
#pragma unroll
        for (int r = 0; r < 4; ++r) {
            int grow = row0 + wm * 64 + i * 16 + lg * 4 + r;
            if (grow < M) {
                float dv = dinv[grow];
#pragma unroll
                for (int j = 0; j < 4; ++j) {
                    int gcol = col0 + wn * 64 + j * 16 + l15;
                    C[(size_t)grow * DFEAT + gcol] = (_Float16)(dv * acc[i][j][r]);
                }
            }
        }
    }
}

// ================= mega2: gemm1 blocks | bin_edges blocks =================
__global__ __launch_bounds__(256, 2) void mega_gemm_bin(const ushort* __restrict__ Ah,
                                                        const ushort* __restrict__ Al,
                                                        const ushort* __restrict__ BhT,
                                                        const ushort* __restrict__ BlT,
                                                        const float* __restrict__ dinv,
                                                        _Float16* __restrict__ C,
                                                        const int2* __restrict__ edges,
                                                        const int* __restrict__ ecount,
                                                        const int* __restrict__ offsets,
                                                        int* __restrict__ cursor,
                                                        int* __restrict__ csc) {
    const int bid = blockIdx.x;
    if (bid < GEMM_BLOCKS) {
        gemm_tile(Ah, Al, BhT, BlT, dinv, C, N_NODES,
                  (bid >> 2) * 128, (bid & 3) * 128, threadIdx.x);
    } else {
        int e = (bid - GEMM_BLOCKS) * 256 + threadIdx.x;
        int E = min(*ecount, EDGE_CAP);
        if (e < E) {
            int2 ij = edges[e];
            int pos = atomicAdd(&cursor[ij.y], 1);
            csc[offsets[ij.y] + pos] = ij.x;
        }
    }
}

// ---------------- plain gemm dispatch (layer 2) ----------------
__global__ __launch_bounds__(256, 2) void gemm2(const ushort* __restrict__ Ah,
                                                const ushort* __restrict__ Al,
                                                const ushort* __restrict__ BhT,
                                                const ushort* __restrict__ BlT,
                                                const float* __restrict__ dinv,
                                                _Float16* __restrict__ C) {
    gemm_tile(Ah, Al, BhT, BlT, dinv, C, N_NODES,
              (blockIdx.x >> 2) * 128, (blockIdx.x & 3) * 128, threadIdx.x);
}

// ---------------- gather core over fp16 rows ----------------
__device__ __forceinline__ float4 gather_sum16(const _Float16* __restrict__ G,
                                               const int* __restrict__ offsets,
                                               const int* __restrict__ csc,
                                               int* sidx, int j, int tid) {
    const half4x* G4 = (const half4x*)G;  // row stride = 128 half4
    half4x h = G4[(j << 7) + tid];        // self row (dinv-prescaled)
    float4 acc = make_float4((float)h[0], (float)h[1], (float)h[2], (float)h[3]);
    int s = offsets[j];
    const int e = offsets[j + 1];
    while (s < e) {
        int chunk = min(128, e - s);
        __syncthreads();
        if (tid < chunk) sidx[tid] = csc[s + tid];
        __syncthreads();
        int c = 0;
        for (; c + 8 <= chunk; c += 8) {
            half4x u[8];
#pragma unroll
            for (int q = 0; q < 8; ++q) u[q] = G4[(sidx[c + q] << 7) + tid];
#pragma unroll
            for (int q = 0; q < 8; ++q) {
                acc.x += (float)u[q][0]; acc.y += (float)u[q][1];
                acc.z += (float)u[q][2]; acc.w += (float)u[q][3];
            }
        }
        for (; c + 4 <= chunk; c += 4) {
            half4x u[4];
#pragma unroll
            for (int q = 0; q < 4; ++q) u[q] = G4[(sidx[c + q] << 7) + tid];
#pragma unroll
            for (int q = 0; q < 4; ++q) {
                acc.x += (float)u[q][0]; acc.y += (float)u[q][1];
                acc.z += (float)u[q][2]; acc.w += (float)u[q][3];
            }
        }
        for (; c < chunk; ++c) {
            half4x u = G4[(sidx[c] << 7) + tid];
            acc.x += (float)u[0]; acc.y += (float)u[1];
            acc.z += (float)u[2]; acc.w += (float)u[3];
        }
        s += chunk;
    }
    return acc;
}

// ---------------- aggregate, bf16 hi/lo split output (layer 1) ----------------
__global__ __launch_bounds__(128) void aggregate_split(const _Float16* __restrict__ G,
                                                       const float* __restrict__ dinv,
                                                       const int* __restrict__ offsets,
                                                       const int* __restrict__ csc,
                                                       const float* __restrict__ bias,
                                                       ushort* __restrict__ Hh,
                                                       ushort* __restrict__ Hl) {
    const int j = blockIdx.x;
    const int tid = threadIdx.x;
    __shared__ int sidx[128];
    float4 acc = gather_sum16(G, offsets, csc, sidx, j, tid);
    const float dj = dinv[j];
    float4 b = ((const float4*)bias)[tid];
    float4 o;
    o.x = fmaxf(dj * acc.x + b.x, 0.0f);
    o.y = fmaxf(dj * acc.y + b.y, 0.0f);
    o.z = fmaxf(dj * acc.z + b.z, 0.0f);
    o.w = fmaxf(dj * acc.w + b.w, 0.0f);
    ushort4 hi, lo;
    hi.x = f2bf(o.x); lo.x = f2bf(o.x - bf2f(hi.x));
    hi.y = f2bf(o.y); lo.y = f2bf(o.y - bf2f(hi.y));
    hi.z = f2bf(o.z); lo.z = f2bf(o.z - bf2f(hi.z));
    hi.w = f2bf(o.w); lo.w = f2bf(o.w - bf2f(hi.w));
    ((ushort4*)(Hh + ((size_t)j << 9)))[tid] = hi;
    ((ushort4*)(Hl + ((size_t)j << 9)))[tid] = lo;
}

// ---------------- aggregate, fp32 output (layer 2) ----------------
__global__ __launch_bounds__(128) void aggregate_final(const _Float16* __restrict__ G,
                                                       const float* __restrict__ dinv,
                                                       const int* __restrict__ offsets,
                                                       const int* __restrict__ csc,
                                                       const float* __restrict__ bias,
                                                       float* __restrict__ out) {
    const int j = blockIdx.x;
    const int tid = threadIdx.x;
    __shared__ int sidx[128];
    float4 acc = gather_sum16(G, offsets, csc, sidx, j, tid);
    const float dj = dinv[j];
    float4 b = ((const float4*)bias)[tid];
    float4 o;
    o.x = fmaxf(dj * acc.x + b.x, 0.0f);
    o.y = fmaxf(dj * acc.y + b.y, 0.0f);
    o.z = fmaxf(dj * acc.z + b.z, 0.0f);
    o.w = fmaxf(dj * acc.w + b.w, 0.0f);
    ((float4*)(out + ((size_t)j << 9)))[tid] = o;
}

extern "C" void kernel_launch(void* const* d_in, const int* in_sizes, int n_in,
                              void* d_out, int out_size, void* d_ws, size_t ws_size,
                              hipStream_t stream) {
    const float* x  = (const float*)d_in[0];
    const float* A  = (const float*)d_in[1];
    const float* W1 = (const float*)d_in[2];
    const float* b1 = (const float*)d_in[3];
    const float* W2 = (const float*)d_in[4];
    const float* b2 = (const float*)d_in[5];
    float* out = (float*)d_out;

    char* ws = (char*)d_ws;
    size_t off = 0;
    auto alloc = [&](size_t bytes) -> void* {
        void* p = ws + off;
        off = (off + bytes + 255) & ~(size_t)255;
        return p;
    };
    _Float16* XW16 = (_Float16*)alloc((size_t)MPAD * DFEAT * 2);
    ushort* Ah   = (ushort*)alloc((size_t)MPAD * DFEAT * 2);
    ushort* Al   = (ushort*)alloc((size_t)MPAD * DFEAT * 2);
    ushort* Hh   = (ushort*)alloc((size_t)MPAD * DFEAT * 2);
    ushort* Hl   = (ushort*)alloc((size_t)MPAD * DFEAT * 2);
    ushort* W1hT = (ushort*)alloc((size_t)DFEAT * DFEAT * 2);
    ushort* W1lT = (ushort*)alloc((size_t)DFEAT * DFEAT * 2);
    ushort* W2hT = (ushort*)alloc((size_t)DFEAT * DFEAT * 2);
    ushort* W2lT = (ushort*)alloc((size_t)DFEAT * DFEAT * 2);
    float*  dinv = (float*)alloc((size_t)N_NODES * 4);
    int*    deg  = (int*)alloc((size_t)N_NODES * 4);   // start of zeroed region
    int*  cursor = (int*)alloc((size_t)N_NODES * 4);
    int*  ecount = (int*)alloc(256);                   // end of zeroed region
    int*    offs = (int*)alloc((size_t)(N_NODES + 1) * 4);
    int2*  edges = (int2*)alloc((size_t)EDGE_CAP * 8);
    int*     csc = (int*)alloc((size_t)EDGE_CAP * 4);

    size_t zbytes = (size_t)((char*)ecount - (char*)deg) + 256;
    hipMemsetAsync(deg, 0, zbytes, stream);

    // 1) fused prep: adjacency scan + x split + W splits (independent, co-scheduled)
    mega_prep<<<NB_SCAN + NB_SPLITX + NB_WSPLIT, 256, 0, stream>>>(
        A, x, W1, W2, deg, edges, ecount, Ah, Al, W1hT, W1lT, W2hT, W2lT);

    // 2) offsets + dinv
    scan_offsets<<<1, 256, 0, stream>>>(deg, offs, dinv);

    // 3) gemm1 (XW16 = dinv .* (x@W1), fp16) fused with edge binning
    mega_gemm_bin<<<GEMM_BLOCKS + BIN_BLOCKS, 256, 0, stream>>>(
        Ah, Al, W1hT, W1lT, dinv, XW16, edges, ecount, offs, cursor, csc);

    // 4) aggregate layer 1 -> bf16 hi/lo H
    aggregate_split<<<N_NODES, 128, 0, stream>>>(XW16, dinv, offs, csc, b1, Hh, Hl);

    // 5) gemm2 -> fp16 prescaled
    gemm2<<<GEMM_BLOCKS, 256, 0, stream>>>(Hh, Hl, W2hT, W2lT, dinv, XW16);

    // 6) aggregate layer 2 -> fp32 out
    aggregate_final<<<N_NODES, 128, 0, stream>>>(XW16, dinv, offs, csc, b2, out);
}